// Round 1
// baseline (988.052 us; speedup 1.0000x reference)
//
#include <hip/hip_runtime.h>
#include <hip/hip_bf16.h>
#include <stdint.h>

#define N_BATCH 4096
#define HID     1024
#define OBSLEN  20

#define BM  128   // batch rows per block
#define BHC 32    // h-columns per block (x4 gates = 128 effective N)
#define BK  64    // K per stage

using short8 = __attribute__((ext_vector_type(8))) short;
using f32x4  = __attribute__((ext_vector_type(4))) float;

__device__ __forceinline__ float rcpf(float x) { return __builtin_amdgcn_rcpf(x); }
__device__ __forceinline__ float sigf(float x) { return rcpf(1.f + __expf(-x)); }
__device__ __forceinline__ float tanh_(float x) {
    float a = fminf(15.f, fmaxf(-15.f, x));
    float t = __expf(-2.f * a);
    return (1.f - t) * rcpf(1.f + t);
}
__device__ __forceinline__ unsigned short f2bf(float f) {
    __hip_bfloat16 b = __float2bfloat16(f);
    return *reinterpret_cast<unsigned short*>(&b);
}
__device__ __forceinline__ float bf2f(unsigned short u) {
    unsigned int x = ((unsigned int)u) << 16;
    return __uint_as_float(x);
}

// ---------------------------------------------------------------- prep ----
// Convert W_hh and h0 to bf16, zero c. All are 4096*1024 elements.
__global__ __launch_bounds__(256) void prep_kernel(
    const float4* __restrict__ Whh, const float4* __restrict__ h0,
    ushort4* __restrict__ Wg, ushort4* __restrict__ hb, float4* __restrict__ c, int n4)
{
    int i = blockIdx.x * 256 + threadIdx.x;
    if (i < n4) {
        float4 w = Whh[i];
        float4 h = h0[i];
        Wg[i] = make_ushort4(f2bf(w.x), f2bf(w.y), f2bf(w.z), f2bf(w.w));
        hb[i] = make_ushort4(f2bf(h.x), f2bf(h.y), f2bf(h.z), f2bf(h.w));
        c[i] = make_float4(0.f, 0.f, 0.f, 0.f);
    }
}

// ---------------------------------------------------------- lstm step ----
// gates[n, g*1024+hc] = sum_k h[n,k]*Whh[g*1024+hc, k]  (+ x/bias part)
// Block: 256 thr (4 waves). Tile: BM=128 rows x BHC=32 hcols x 4 gates.
// Wave (wr=wid>>1, wc=wid&1): 64 rows x 16 hcols x 4 gates.
// LDS per buffer: A[128][64] bf16 (16KB) + B[4][32][64] bf16 (16KB). 2 buffers.
// Both tiles content-swizzled: element (row,kbyte) lives at row*128 + (kbyte ^ ((row&7)<<4)).
__global__ __launch_bounds__(256, 2) void lstm_step_kernel(
    const ushort* __restrict__ hin,   // [4096][1024] bf16
    const ushort* __restrict__ Wg,    // [4096][1024] bf16
    const float*  __restrict__ xt,    // [4096][2]
    const float*  __restrict__ Wih,   // [4096][2]
    const float*  __restrict__ bih,
    const float*  __restrict__ bhh,
    float*        __restrict__ cst,   // [4096][1024] fp32 state
    ushort*       __restrict__ hout)  // [4096][1024] bf16
{
    __shared__ __align__(16) char lds[65536];
    const int tid  = threadIdx.x;
    const int wid  = tid >> 6, lane = tid & 63;
    const int l15  = lane & 15, l4 = lane >> 4;
    const int m0   = blockIdx.x * BM;
    const int h0c  = blockIdx.y * BHC;
    const int wr   = wid >> 1, wc = wid & 1;

    // staging geometry: per thread 16B per round, 4 rounds per tile.
    const int rowS = tid >> 3;                                   // 0..31
    const int offS = ((tid & 7) * 16) ^ ((rowS & 7) << 4);       // swizzled source byte in 128B row
    const ushort* aSrc0 = hin + (size_t)(m0 + rowS) * HID + (offS >> 1);
    const ushort* bSrc0 = Wg  + (size_t)(h0c + rowS) * HID + (offS >> 1);

    auto stage = [&](int buf, int k0) {
        char* ab = lds + buf * 32768 + tid * 16;
        char* bb = ab + 16384;
        const ushort* as = aSrc0 + k0;
        const ushort* bs = bSrc0 + k0;
#pragma unroll
        for (int r = 0; r < 4; ++r) {
            // A round r: rows r*32 .. r*32+31
            __builtin_amdgcn_global_load_lds(
                (const __attribute__((address_space(1))) void*)(as + (size_t)r * 32 * HID),
                (__attribute__((address_space(3))) void*)(ab + r * 4096), 16, 0, 0);
            // B round r: gate r, rows h0c..h0c+31 of quadrant r
            __builtin_amdgcn_global_load_lds(
                (const __attribute__((address_space(1))) void*)(bs + (size_t)r * 1024 * HID),
                (__attribute__((address_space(3))) void*)(bb + r * 4096), 16, 0, 0);
        }
    };

    f32x4 acc[4][4]; // [row frag][gate]
#pragma unroll
    for (int a = 0; a < 4; ++a)
#pragma unroll
        for (int b = 0; b < 4; ++b)
            acc[a][b] = (f32x4){0.f, 0.f, 0.f, 0.f};

    stage(0, 0);
    __syncthreads();

    const int swz = (l15 & 7) << 4;
    const int NK = HID / BK; // 16
    for (int kt = 0; kt < NK; ++kt) {
        const int cur = kt & 1;
        if (kt < NK - 1) stage(cur ^ 1, (kt + 1) * BK);

        const char* A = lds + cur * 32768;
        const char* B = A + 16384;
#pragma unroll
        for (int kk = 0; kk < 2; ++kk) {
            const int kb = (kk * 64 + l4 * 16) ^ swz;
            short8 af[4], bfr[4];
#pragma unroll
            for (int fr = 0; fr < 4; ++fr) {
                int row = wr * 64 + fr * 16 + l15;
                af[fr] = *(const short8*)(A + row * 128 + kb);
            }
#pragma unroll
            for (int g = 0; g < 4; ++g) {
                int hc = wc * 16 + l15;
                bfr[g] = *(const short8*)(B + g * 4096 + hc * 128 + kb);
            }
#pragma unroll
            for (int fr = 0; fr < 4; ++fr)
#pragma unroll
                for (int g = 0; g < 4; ++g)
                    acc[fr][g] = __builtin_amdgcn_mfma_f32_16x16x32_bf16(af[fr], bfr[g], acc[fr][g], 0, 0, 0);
        }
        __syncthreads(); // drains vmcnt+lgkmcnt (compiler semantics) -> next buffer ready
    }

    // ---------------- epilogue: fused LSTM pointwise update ----------------
    const int hcg = h0c + wc * 16 + l15;  // global h column for this lane
    float wi0[4], wi1[4], bs_[4];
#pragma unroll
    for (int g = 0; g < 4; ++g) {
        int j = g * HID + hcg;
        wi0[g] = Wih[j * 2 + 0];
        wi1[g] = Wih[j * 2 + 1];
        bs_[g] = bih[j] + bhh[j];
    }
#pragma unroll
    for (int fr = 0; fr < 4; ++fr) {
#pragma unroll
        for (int r = 0; r < 4; ++r) {
            int n = m0 + wr * 64 + fr * 16 + l4 * 4 + r;
            float x0 = xt[n * 2 + 0], x1 = xt[n * 2 + 1];
            float gi = acc[fr][0][r] + x0 * wi0[0] + x1 * wi1[0] + bs_[0];
            float gf = acc[fr][1][r] + x0 * wi0[1] + x1 * wi1[1] + bs_[1];
            float gg = acc[fr][2][r] + x0 * wi0[2] + x1 * wi1[2] + bs_[2];
            float go = acc[fr][3][r] + x0 * wi0[3] + x1 * wi1[3] + bs_[3];
            float iv = sigf(gi), fv = sigf(gf);
            float gv = tanh_(gg), ov = sigf(go);
            size_t idx = (size_t)n * HID + hcg;
            float cn = fv * cst[idx] + iv * gv;
            cst[idx]  = cn;
            hout[idx] = f2bf(ov * tanh_(cn));
        }
    }
}

// ----------------------------------------------------------- out proj ----
// out[n, c] = sum_k h[n,k] * W_out[c,k] + b_out[c]; wave per row.
__global__ __launch_bounds__(256) void out_proj_kernel(
    const ushort* __restrict__ h, const float* __restrict__ Wout,
    const float* __restrict__ bout, float* __restrict__ outt)
{
    const int wid = threadIdx.x >> 6, lane = threadIdx.x & 63;
    const int row = blockIdx.x * 4 + wid;
    const ushort* hr = h + (size_t)row * HID + lane * 16;
    float a0 = 0.f, a1 = 0.f;
#pragma unroll
    for (int half = 0; half < 2; ++half) {
        short8 hv = *(const short8*)(hr + half * 8);
#pragma unroll
        for (int j = 0; j < 8; ++j) {
            int k = lane * 16 + half * 8 + j;
            float f = bf2f((unsigned short)hv[j]);
            a0 += f * Wout[k];
            a1 += f * Wout[HID + k];
        }
    }
#pragma unroll
    for (int off = 32; off > 0; off >>= 1) {
        a0 += __shfl_down(a0, off);
        a1 += __shfl_down(a1, off);
    }
    if (lane == 0) {
        outt[row * 2 + 0] = a0 + bout[0];
        outt[row * 2 + 1] = a1 + bout[1];
    }
}

// ------------------------------------------------------------- launch ----
extern "C" void kernel_launch(void* const* d_in, const int* in_sizes, int n_in,
                              void* d_out, int out_size, void* d_ws, size_t ws_size,
                              hipStream_t stream) {
    const float* obs  = (const float*)d_in[0];
    const float* h0   = (const float*)d_in[1];
    const float* Wih  = (const float*)d_in[2];
    const float* Whh  = (const float*)d_in[3];
    const float* bih  = (const float*)d_in[4];
    const float* bhh  = (const float*)d_in[5];
    const float* Wout = (const float*)d_in[6];
    const float* bout = (const float*)d_in[7];
    float* out = (float*)d_out;

    char* ws = (char*)d_ws;
    ushort* Wg = (ushort*)(ws);                 // 8 MB bf16 W_hh
    ushort* hA = (ushort*)(ws + (8  << 20));    // 8 MB bf16 h ping
    ushort* hB = (ushort*)(ws + (16 << 20));    // 8 MB bf16 h pong
    float*  c  = (float* )(ws + (24 << 20));    // 16 MB fp32 c state

    prep_kernel<<<4096, 256, 0, stream>>>((const float4*)Whh, (const float4*)h0,
                                          (ushort4*)Wg, (ushort4*)hA, (float4*)c,
                                          N_BATCH * HID / 4);

    ushort* hin = hA;
    ushort* hou = hB;
    for (int t = 0; t < OBSLEN; ++t) {
        const float* xt = obs + (size_t)(t == 0 ? 0 : (t - 1)) * N_BATCH * 2;
        lstm_step_kernel<<<dim3(N_BATCH / BM, HID / BHC), 256, 0, stream>>>(
            hin, Wg, xt, Wih, bih, bhh, c, hou);
        out_proj_kernel<<<N_BATCH / 4, 256, 0, stream>>>(
            hou, Wout, bout, out + (size_t)t * N_BATCH * 2);
        ushort* tmp = hin; hin = hou; hou = tmp;
    }
}

// Round 2
// 892.424 us; speedup vs baseline: 1.1072x; 1.1072x over previous
//
#include <hip/hip_runtime.h>
#include <hip/hip_bf16.h>
#include <stdint.h>

#define N_BATCH 4096
#define HID     1024
#define OBSLEN  20

#define BM  256   // batch rows per block
#define BHC 64    // h-columns per block (x4 gates = 256 effective N)
#define BK  64    // K per stage

using short8 = __attribute__((ext_vector_type(8))) short;
using f32x4  = __attribute__((ext_vector_type(4))) float;

#define AS1 __attribute__((address_space(1)))
#define AS3 __attribute__((address_space(3)))

__device__ __forceinline__ float rcpf(float x) { return __builtin_amdgcn_rcpf(x); }
__device__ __forceinline__ float sigf(float x) { return rcpf(1.f + __expf(-x)); }
__device__ __forceinline__ float tanh_(float x) {
    float a = fminf(15.f, fmaxf(-15.f, x));
    float t = __expf(-2.f * a);
    return (1.f - t) * rcpf(1.f + t);
}
__device__ __forceinline__ unsigned short f2bf(float f) {
    __hip_bfloat16 b = __float2bfloat16(f);
    return *reinterpret_cast<unsigned short*>(&b);
}
__device__ __forceinline__ float bf2f(unsigned short u) {
    unsigned int x = ((unsigned int)u) << 16;
    return __uint_as_float(x);
}

// ---------------------------------------------------------------- prep ----
__global__ __launch_bounds__(256) void prep_kernel(
    const float4* __restrict__ Whh, const float4* __restrict__ h0,
    ushort4* __restrict__ Wg, ushort4* __restrict__ hb, float4* __restrict__ c, int n4)
{
    int i = blockIdx.x * 256 + threadIdx.x;
    if (i < n4) {
        float4 w = Whh[i];
        float4 h = h0[i];
        Wg[i] = make_ushort4(f2bf(w.x), f2bf(w.y), f2bf(w.z), f2bf(w.w));
        hb[i] = make_ushort4(f2bf(h.x), f2bf(h.y), f2bf(h.z), f2bf(h.w));
        c[i] = make_float4(0.f, 0.f, 0.f, 0.f);
    }
}

// ---------------------------------------------------------- lstm step ----
// 512 thr = 8 waves (wr = wid>>2 in {0,1}: 128 rows; wc = wid&3: 16 hcols x 4 gates).
// LDS 128 KB: A[2][256][64]bf16 @ 0, B[2][4][64][64]bf16 @ 65536.
// Content swizzle (both sides): element (row,kbyte) at row*128 + (kbyte ^ ((row&7)<<4)).
// Pipeline: tile kt+1 staged during tile kt's 4 phases (2 loads/thr/phase,
// A rounds at ph1/ph2, B rounds at ph3/ph4); counted vmcnt(2) + barrier at
// ph1/ph2 only; no drain-to-0 in steady state (T3+T4), setprio around MFMA (T5).
__global__ __launch_bounds__(512, 2) void lstm_step_kernel(
    const ushort* __restrict__ hin,   // [4096][1024] bf16
    const ushort* __restrict__ Wg,    // [4096][1024] bf16 (gate-major rows)
    const float*  __restrict__ xt,    // [4096][2]
    const float*  __restrict__ Wih,   // [4096][2]
    const float*  __restrict__ bih,
    const float*  __restrict__ bhh,
    float*        __restrict__ cst,   // [4096][1024] fp32 state
    ushort*       __restrict__ hout)  // [4096][1024] bf16
{
    __shared__ __align__(16) char lds[131072];
    const int tid  = threadIdx.x;
    const int lane = tid & 63, l15 = lane & 15, l4 = lane >> 4;
    const int wid  = tid >> 6, wr = wid >> 2, wc = wid & 3;
    const int m0   = blockIdx.x * BM;
    const int h0c  = blockIdx.y * BHC;

    // ---- staging geometry (per thread: 16B, 64 rows per 8KB round) ----
    const int rowS = tid >> 3;                                  // 0..63
    const int offS = ((tid & 7) * 16) ^ ((rowS & 7) << 4);      // swizzled src byte in 128B row
    const ushort* aS = hin + (size_t)(m0 + rowS) * HID + (offS >> 1);
    const ushort* bS = Wg  + (size_t)(h0c + rowS) * HID + (offS >> 1);
    char* aD = lds + tid * 16;           // + buf*32768 + r*8192
    char* bD = lds + 65536 + tid * 16;

    auto stA = [&](int buf, int kt1, int r) {
        __builtin_amdgcn_global_load_lds(
            (const AS1 void*)(aS + kt1 * BK + (size_t)r * 64 * HID),
            (AS3 void*)(aD + buf * 32768 + r * 8192), 16, 0, 0);
    };
    auto stB = [&](int buf, int kt1, int r) {
        __builtin_amdgcn_global_load_lds(
            (const AS1 void*)(bS + kt1 * BK + (size_t)r * 1024 * HID),
            (AS3 void*)(bD + buf * 32768 + r * 8192), 16, 0, 0);
    };

    // ---- ds_read per-lane offsets ----
    const int swz  = (l15 & 7) << 4;
    const int aOff = (wr * 128 + l15) * 128 + ((l4 * 16) ^ swz); // frag f: +f*2048 ; kk1: ^64
    const int bOff = (wc * 16  + l15) * 128 + ((l4 * 16) ^ swz); // gate g: +g*8192 ; kk1: ^64

    f32x4 acc[8][4];
#pragma unroll
    for (int f = 0; f < 8; ++f)
#pragma unroll
        for (int g = 0; g < 4; ++g)
            acc[f][g] = (f32x4){0.f, 0.f, 0.f, 0.f};

    // prologue: stage tile 0 fully (8 loads in flight)
#pragma unroll
    for (int r = 0; r < 4; ++r) stA(0, 0, r);
#pragma unroll
    for (int r = 0; r < 4; ++r) stB(0, 0, r);

    const int NK = HID / BK; // 16
    for (int kt = 0; kt < NK; ++kt) {
        const int cur = kt & 1, nxt = cur ^ 1;
        const bool st = (kt < NK - 1);
        const char* A = lds + cur * 32768;
        const char* B = lds + 65536 + cur * 32768;

        short8 af[8], bf0, bf1, bf2, bf3;

        // ---------------- phase 1: A frags + B g0,g1 @ kk0 ----------------
        asm volatile("s_waitcnt vmcnt(2)" ::: "memory");
        __builtin_amdgcn_s_barrier();
        __builtin_amdgcn_sched_barrier(0);
#pragma unroll
        for (int f = 0; f < 8; ++f)
            af[f] = *(const short8*)(A + aOff + f * 2048);
        bf0 = *(const short8*)(B + bOff);
        bf1 = *(const short8*)(B + bOff + 8192);
        if (st) { stA(nxt, kt + 1, 0); stA(nxt, kt + 1, 1); }
        __builtin_amdgcn_s_setprio(1);
#pragma unroll
        for (int f = 0; f < 8; ++f) {
            acc[f][0] = __builtin_amdgcn_mfma_f32_16x16x32_bf16(af[f], bf0, acc[f][0], 0, 0, 0);
            acc[f][1] = __builtin_amdgcn_mfma_f32_16x16x32_bf16(af[f], bf1, acc[f][1], 0, 0, 0);
        }
        __builtin_amdgcn_s_setprio(0);

        // ---------------- phase 2: B g2,g3 @ kk0 ----------------
        if (st) asm volatile("s_waitcnt vmcnt(2)" ::: "memory");
        else    asm volatile("s_waitcnt vmcnt(0)" ::: "memory");
        __builtin_amdgcn_s_barrier();
        __builtin_amdgcn_sched_barrier(0);
        bf2 = *(const short8*)(B + bOff + 16384);
        bf3 = *(const short8*)(B + bOff + 24576);
        if (st) { stA(nxt, kt + 1, 2); stA(nxt, kt + 1, 3); }
        __builtin_amdgcn_s_setprio(1);
#pragma unroll
        for (int f = 0; f < 8; ++f) {
            acc[f][2] = __builtin_amdgcn_mfma_f32_16x16x32_bf16(af[f], bf2, acc[f][2], 0, 0, 0);
            acc[f][3] = __builtin_amdgcn_mfma_f32_16x16x32_bf16(af[f], bf3, acc[f][3], 0, 0, 0);
        }
        __builtin_amdgcn_s_setprio(0);

        // ---------------- phase 3: A frags + B g0,g1 @ kk1 (no barrier) ----
#pragma unroll
        for (int f = 0; f < 8; ++f)
            af[f] = *(const short8*)(A + (aOff ^ 64) + f * 2048);
        bf0 = *(const short8*)(B + (bOff ^ 64));
        bf1 = *(const short8*)(B + (bOff ^ 64) + 8192);
        if (st) { stB(nxt, kt + 1, 0); stB(nxt, kt + 1, 1); }
        __builtin_amdgcn_s_setprio(1);
#pragma unroll
        for (int f = 0; f < 8; ++f) {
            acc[f][0] = __builtin_amdgcn_mfma_f32_16x16x32_bf16(af[f], bf0, acc[f][0], 0, 0, 0);
            acc[f][1] = __builtin_amdgcn_mfma_f32_16x16x32_bf16(af[f], bf1, acc[f][1], 0, 0, 0);
        }
        __builtin_amdgcn_s_setprio(0);

        // ---------------- phase 4: B g2,g3 @ kk1 (no barrier) ----------------
        bf2 = *(const short8*)(B + (bOff ^ 64) + 16384);
        bf3 = *(const short8*)(B + (bOff ^ 64) + 24576);
        if (st) { stB(nxt, kt + 1, 2); stB(nxt, kt + 1, 3); }
        __builtin_amdgcn_s_setprio(1);
#pragma unroll
        for (int f = 0; f < 8; ++f) {
            acc[f][2] = __builtin_amdgcn_mfma_f32_16x16x32_bf16(af[f], bf2, acc[f][2], 0, 0, 0);
            acc[f][3] = __builtin_amdgcn_mfma_f32_16x16x32_bf16(af[f], bf3, acc[f][3], 0, 0, 0);
        }
        __builtin_amdgcn_s_setprio(0);
    }

    // ---------------- epilogue: fused LSTM pointwise update ----------------
    const int hcg = h0c + wc * 16 + l15;
    float wi0[4], wi1[4], bs_[4];
#pragma unroll
    for (int g = 0; g < 4; ++g) {
        int j = g * HID + hcg;
        wi0[g] = Wih[j * 2 + 0];
        wi1[g] = Wih[j * 2 + 1];
        bs_[g] = bih[j] + bhh[j];
    }
#pragma unroll
    for (int f = 0; f < 8; ++f) {
#pragma unroll
        for (int r = 0; r < 4; ++r) {
            int n = m0 + wr * 128 + f * 16 + l4 * 4 + r;
            float x0 = xt[n * 2 + 0], x1 = xt[n * 2 + 1];
            float gi = acc[f][0][r] + x0 * wi0[0] + x1 * wi1[0] + bs_[0];
            float gf = acc[f][1][r] + x0 * wi0[1] + x1 * wi1[1] + bs_[1];
            float gg = acc[f][2][r] + x0 * wi0[2] + x1 * wi1[2] + bs_[2];
            float go = acc[f][3][r] + x0 * wi0[3] + x1 * wi1[3] + bs_[3];
            float iv = sigf(gi), fv = sigf(gf);
            float gv = tanh_(gg), ov = sigf(go);
            size_t idx = (size_t)n * HID + hcg;
            float cn = fv * cst[idx] + iv * gv;
            cst[idx]  = cn;
            hout[idx] = f2bf(ov * tanh_(cn));
        }
    }
}

// ----------------------------------------------------------- out proj ----
__global__ __launch_bounds__(256) void out_proj_kernel(
    const ushort* __restrict__ h, const float* __restrict__ Wout,
    const float* __restrict__ bout, float* __restrict__ outt)
{
    const int wid = threadIdx.x >> 6, lane = threadIdx.x & 63;
    const int row = blockIdx.x * 4 + wid;
    const ushort* hr = h + (size_t)row * HID + lane * 16;
    float a0 = 0.f, a1 = 0.f;
#pragma unroll
    for (int half = 0; half < 2; ++half) {
        short8 hv = *(const short8*)(hr + half * 8);
#pragma unroll
        for (int j = 0; j < 8; ++j) {
            int k = lane * 16 + half * 8 + j;
            float f = bf2f((unsigned short)hv[j]);
            a0 += f * Wout[k];
            a1 += f * Wout[HID + k];
        }
    }
#pragma unroll
    for (int off = 32; off > 0; off >>= 1) {
        a0 += __shfl_down(a0, off);
        a1 += __shfl_down(a1, off);
    }
    if (lane == 0) {
        outt[row * 2 + 0] = a0 + bout[0];
        outt[row * 2 + 1] = a1 + bout[1];
    }
}

// ------------------------------------------------------------- launch ----
extern "C" void kernel_launch(void* const* d_in, const int* in_sizes, int n_in,
                              void* d_out, int out_size, void* d_ws, size_t ws_size,
                              hipStream_t stream) {
    const float* obs  = (const float*)d_in[0];
    const float* h0   = (const float*)d_in[1];
    const float* Wih  = (const float*)d_in[2];
    const float* Whh  = (const float*)d_in[3];
    const float* bih  = (const float*)d_in[4];
    const float* bhh  = (const float*)d_in[5];
    const float* Wout = (const float*)d_in[6];
    const float* bout = (const float*)d_in[7];
    float* out = (float*)d_out;

    char* ws = (char*)d_ws;
    ushort* Wg = (ushort*)(ws);                 // 8 MB bf16 W_hh
    ushort* hA = (ushort*)(ws + (8  << 20));    // 8 MB bf16 h ping
    ushort* hB = (ushort*)(ws + (16 << 20));    // 8 MB bf16 h pong
    float*  c  = (float* )(ws + (24 << 20));    // 16 MB fp32 c state

    prep_kernel<<<4096, 256, 0, stream>>>((const float4*)Whh, (const float4*)h0,
                                          (ushort4*)Wg, (ushort4*)hA, (float4*)c,
                                          N_BATCH * HID / 4);

    ushort* hin = hA;
    ushort* hou = hB;
    for (int t = 0; t < OBSLEN; ++t) {
        const float* xt = obs + (size_t)(t == 0 ? 0 : (t - 1)) * N_BATCH * 2;
        lstm_step_kernel<<<dim3(N_BATCH / BM, HID / BHC), 512, 0, stream>>>(
            hin, Wg, xt, Wih, bih, bhh, c, hou);
        out_proj_kernel<<<N_BATCH / 4, 256, 0, stream>>>(
            hou, Wout, bout, out + (size_t)t * N_BATCH * 2);
        ushort* tmp = hin; hin = hou; hou = tmp;
    }
}

// Round 4
// 860.962 us; speedup vs baseline: 1.1476x; 1.0365x over previous
//
#include <hip/hip_runtime.h>
#include <hip/hip_bf16.h>
#include <stdint.h>

#define N_BATCH 4096
#define HID     1024
#define OBSLEN  20

#define BM  256   // batch rows per block
#define BK  64    // K per stage
// Block owns 256 output cols = 64 hcols x 4 gates, gate-interleaved (see prep).
// Output matrix is [4096 rows][4*HID=4096 cols] -> grid (16, 16).

using short8 = __attribute__((ext_vector_type(8))) short;
using f32x4  = __attribute__((ext_vector_type(4))) float;

#define AS1 __attribute__((address_space(1)))
#define AS3 __attribute__((address_space(3)))

__device__ __forceinline__ float rcpf(float x) { return __builtin_amdgcn_rcpf(x); }
__device__ __forceinline__ float sigf(float x) { return rcpf(1.f + __expf(-x)); }
__device__ __forceinline__ float tanh_(float x) {
    float a = fminf(15.f, fmaxf(-15.f, x));
    float t = __expf(-2.f * a);
    return (1.f - t) * rcpf(1.f + t);
}
__device__ __forceinline__ unsigned short f2bf(float f) {
    __hip_bfloat16 b = __float2bfloat16(f);
    return *reinterpret_cast<unsigned short*>(&b);
}
__device__ __forceinline__ float bf2f(unsigned short u) {
    unsigned int x = ((unsigned int)u) << 16;
    return __uint_as_float(x);
}

// ---------------------------------------------------------------- prep ----
// hA = bf16(h0); cst = 0; Wg = bf16(W_hh) with gate-interleaved row permutation:
// dest row R = by*256 + c'  (by in [0,16) = hcol-group, c' in [0,256)):
//   gate g = (c'>>4)&3, hcol_local = ((c'>>6)<<4) | (c'&15)
//   source row = g*1024 + by*64 + hcol_local
__global__ __launch_bounds__(256) void prep_kernel(
    const float4* __restrict__ Whh, const float4* __restrict__ h0,
    ushort4* __restrict__ Wg, ushort4* __restrict__ hb, float4* __restrict__ c, int n4)
{
    int i = blockIdx.x * 256 + threadIdx.x;
    if (i < n4) {
        float4 h = h0[i];
        hb[i] = make_ushort4(f2bf(h.x), f2bf(h.y), f2bf(h.z), f2bf(h.w));
        c[i] = make_float4(0.f, 0.f, 0.f, 0.f);
        int R  = i >> 8, k4 = i & 255;
        int by = R >> 8, cp = R & 255;
        int g  = (cp >> 4) & 3;
        int hl = ((cp >> 6) << 4) | (cp & 15);
        int orig = g * HID + by * 64 + hl;
        float4 w = Whh[orig * 256 + k4];
        Wg[i] = make_ushort4(f2bf(w.x), f2bf(w.y), f2bf(w.z), f2bf(w.w));
    }
}

// ---------------------------------------------------------- lstm step ----
// 512 thr = 8 waves. Wave (wr=wid>>2, wc=wid&3): 128 rows x 64 cols.
// LDS 128KB: A[2][256][64]bf16 @0, B[2][256][64]bf16 @65536.
// Content swizzle: element (row,kbyte) at row*128 + (kbyte ^ ((row&7)<<4)).
// 4 phases/K-tile, 16 MFMA each; staging for tile kt+1 spread 3/3/2 across
// ph1-3 in order B0,B1,B2 | B3,A0,A2 | A1,A3; counted vmcnt (never 0 mid-loop).
__global__ __launch_bounds__(512, 2) void lstm_step_kernel(
    const ushort* __restrict__ hin,   // [4096][1024] bf16 canonical
    const ushort* __restrict__ Wg,    // [4096][1024] bf16 permuted rows
    const float*  __restrict__ xt,    // [4096][2]
    const float*  __restrict__ Wih,   // [4096][2]
    const float*  __restrict__ bih,
    const float*  __restrict__ bhh,
    float*        __restrict__ cst,   // per-block [f][tid] float4 layout
    ushort*       __restrict__ hout)  // [4096][1024] bf16 canonical
{
    __shared__ __align__(16) char lds[131072];
    const int tid  = threadIdx.x;
    const int lane = tid & 63, l15 = lane & 15, l4 = lane >> 4;
    const int wid  = tid >> 6, wr = wid >> 2, wc = wid & 3;
    const int m0   = blockIdx.x * BM;
    const int by   = blockIdx.y;                       // [0,16) hcol-group
    const int bid  = blockIdx.y * (N_BATCH / BM) + blockIdx.x;

    // ---- staging geometry (per thread 16B; one round = 64 rows = 8KB) ----
    const int rowS = tid >> 3;                                  // 0..63
    const int offS = ((tid & 7) * 16) ^ ((rowS & 7) << 4);      // inverse-swizzled src byte
    const ushort* aS = hin + (size_t)(m0 + rowS) * HID + (offS >> 1);
    const ushort* bS = Wg  + (size_t)(by * 256 + rowS) * HID + (offS >> 1);
    char* aD = lds + tid * 16;
    char* bD = lds + 65536 + tid * 16;

    auto stA = [&](int buf, int k0, int r) {
        __builtin_amdgcn_global_load_lds(
            (const AS1 void*)(aS + k0 + (size_t)r * 64 * HID),
            (AS3 void*)(aD + buf * 32768 + r * 8192), 16, 0, 0);
    };
    auto stB = [&](int buf, int k0, int r) {
        __builtin_amdgcn_global_load_lds(
            (const AS1 void*)(bS + k0 + (size_t)r * 64 * HID),
            (AS3 void*)(bD + buf * 32768 + r * 8192), 16, 0, 0);
    };

    // ---- ds_read per-lane offsets ----
    const int swz   = (l15 & 7) << 4;
    const int kb0   = (l4 * 16) ^ swz;                // kk1 = ^64 (bit-disjoint)
    const int aBase = (wr * 128 + l15) * 128 + kb0;   // frag f: +f*2048
    const int bBase = (wc * 64  + l15) * 128 + kb0;   // col frag n: +n*2048

    f32x4 acc[8][4];
#pragma unroll
    for (int f = 0; f < 8; ++f)
#pragma unroll
        for (int n = 0; n < 4; ++n)
            acc[f][n] = (f32x4){0.f, 0.f, 0.f, 0.f};

    // prologue staging, steady-state issue order: B0,B1,B2,B3,A0,A2,A1,A3
    stB(0, 0, 0); stB(0, 0, 1); stB(0, 0, 2); stB(0, 0, 3);
    stA(0, 0, 0); stA(0, 0, 2); stA(0, 0, 1); stA(0, 0, 3);

    short8 af[4], bfr[4];
    const int NK = HID / BK; // 16
    for (int kt = 0; kt < NK; ++kt) {
        const int cur = kt & 1, nxt = cur ^ 1;
        const bool st = (kt < NK - 1);
        const int k1 = (kt + 1) * BK;
        const char* A = lds + cur * 32768;
        const char* B = lds + 65536 + cur * 32768;

        // ---- phase 1: kk0, frags 0-3, all 4 col-frags ----
        asm volatile("s_waitcnt vmcnt(2)" ::: "memory");   // need B0-3,A0,A2; leave A1,A3
        __builtin_amdgcn_s_barrier();
        __builtin_amdgcn_sched_barrier(0);
#pragma unroll
        for (int f = 0; f < 4; ++f) af[f]  = *(const short8*)(A + aBase + f * 2048);
#pragma unroll
        for (int n = 0; n < 4; ++n) bfr[n] = *(const short8*)(B + bBase + n * 2048);
        if (st) { stB(nxt, k1, 0); stB(nxt, k1, 1); stB(nxt, k1, 2); }
        asm volatile("s_waitcnt lgkmcnt(0)" ::: "memory");
        __builtin_amdgcn_sched_barrier(0);
        __builtin_amdgcn_s_setprio(1);
#pragma unroll
        for (int f = 0; f < 4; ++f)
#pragma unroll
            for (int n = 0; n < 4; ++n)
                acc[f][n] = __builtin_amdgcn_mfma_f32_16x16x32_bf16(af[f], bfr[n], acc[f][n], 0, 0, 0);
        __builtin_amdgcn_s_setprio(0);

        // ---- phase 2: kk0, frags 4-7 (reuse bfr) ----
        if (st) asm volatile("s_waitcnt vmcnt(3)" ::: "memory");  // need A1,A3; leave 3 new B
        else    asm volatile("s_waitcnt vmcnt(0)" ::: "memory");
        __builtin_amdgcn_s_barrier();
        __builtin_amdgcn_sched_barrier(0);
#pragma unroll
        for (int f = 0; f < 4; ++f) af[f] = *(const short8*)(A + aBase + (f + 4) * 2048);
        if (st) { stB(nxt, k1, 3); stA(nxt, k1, 0); stA(nxt, k1, 2); }
        asm volatile("s_waitcnt lgkmcnt(0)" ::: "memory");
        __builtin_amdgcn_sched_barrier(0);
        __builtin_amdgcn_s_setprio(1);
#pragma unroll
        for (int f = 0; f < 4; ++f)
#pragma unroll
            for (int n = 0; n < 4; ++n)
                acc[f + 4][n] = __builtin_amdgcn_mfma_f32_16x16x32_bf16(af[f], bfr[n], acc[f + 4][n], 0, 0, 0);
        __builtin_amdgcn_s_setprio(0);

        // ---- phase 3: kk1, frags 0-3 ----
        __builtin_amdgcn_s_barrier();
        __builtin_amdgcn_sched_barrier(0);
#pragma unroll
        for (int f = 0; f < 4; ++f) af[f]  = *(const short8*)(A + (aBase ^ 64) + f * 2048);
#pragma unroll
        for (int n = 0; n < 4; ++n) bfr[n] = *(const short8*)(B + (bBase ^ 64) + n * 2048);
        if (st) { stA(nxt, k1, 1); stA(nxt, k1, 3); }
        asm volatile("s_waitcnt lgkmcnt(0)" ::: "memory");
        __builtin_amdgcn_sched_barrier(0);
        __builtin_amdgcn_s_setprio(1);
#pragma unroll
        for (int f = 0; f < 4; ++f)
#pragma unroll
            for (int n = 0; n < 4; ++n)
                acc[f][n] = __builtin_amdgcn_mfma_f32_16x16x32_bf16(af[f], bfr[n], acc[f][n], 0, 0, 0);
        __builtin_amdgcn_s_setprio(0);

        // ---- phase 4: kk1, frags 4-7 ----
        __builtin_amdgcn_s_barrier();
        __builtin_amdgcn_sched_barrier(0);
#pragma unroll
        for (int f = 0; f < 4; ++f) af[f] = *(const short8*)(A + (aBase ^ 64) + (f + 4) * 2048);
        asm volatile("s_waitcnt lgkmcnt(0)" ::: "memory");
        __builtin_amdgcn_sched_barrier(0);
        __builtin_amdgcn_s_setprio(1);
#pragma unroll
        for (int f = 0; f < 4; ++f)
#pragma unroll
            for (int n = 0; n < 4; ++n)
                acc[f + 4][n] = __builtin_amdgcn_mfma_f32_16x16x32_bf16(af[f], bfr[n], acc[f + 4][n], 0, 0, 0);
        __builtin_amdgcn_s_setprio(0);
    }

    // ---------------- epilogue: fused LSTM pointwise update ----------------
    float4* c4 = (float4*)cst + (size_t)bid * 4096;   // [f][tid] float4
    float4 cv[8];
#pragma unroll
    for (int f = 0; f < 8; ++f) cv[f] = c4[f * 512 + tid];

    const int hcg = by * 64 + wc * 16 + l15;          // global h column
    float wi0[4], wi1[4], bs_[4];
#pragma unroll
    for (int n = 0; n < 4; ++n) {
        int j = n * HID + hcg;
        wi0[n] = Wih[j * 2 + 0];
        wi1[n] = Wih[j * 2 + 1];
        bs_[n] = bih[j] + bhh[j];
    }
    const float2* xt2 = (const float2*)xt;
#pragma unroll
    for (int f = 0; f < 8; ++f) {
#pragma unroll
        for (int r = 0; r < 4; ++r) {
            int nrow = m0 + wr * 128 + f * 16 + l4 * 4 + r;
            float2 x = xt2[nrow];
            float gi = acc[f][0][r] + x.x * wi0[0] + x.y * wi1[0] + bs_[0];
            float gf = acc[f][1][r] + x.x * wi0[1] + x.y * wi1[1] + bs_[1];
            float gg = acc[f][2][r] + x.x * wi0[2] + x.y * wi1[2] + bs_[2];
            float go = acc[f][3][r] + x.x * wi0[3] + x.y * wi1[3] + bs_[3];
            float iv = sigf(gi), fv = sigf(gf);
            float gv = tanh_(gg), ov = sigf(go);
            float cn = fv * cv[f][r] + iv * gv;
            cv[f][r] = cn;
            hout[(size_t)nrow * HID + hcg] = f2bf(ov * tanh_(cn));
        }
        c4[f * 512 + tid] = cv[f];
    }
}

// ----------------------------------------------------------- out proj ----
__global__ __launch_bounds__(256) void out_proj_kernel(
    const ushort* __restrict__ h, const float* __restrict__ Wout,
    const float* __restrict__ bout, float* __restrict__ outt)
{
    const int wid = threadIdx.x >> 6, lane = threadIdx.x & 63;
    const int row = blockIdx.x * 4 + wid;
    const ushort* hr = h + (size_t)row * HID + lane * 16;
    float a0 = 0.f, a1 = 0.f;
#pragma unroll
    for (int half = 0; half < 2; ++half) {
        short8 hv = *(const short8*)(hr + half * 8);
#pragma unroll
        for (int j = 0; j < 8; ++j) {
            int k = lane * 16 + half * 8 + j;
            float f = bf2f((unsigned short)hv[j]);
            a0 += f * Wout[k];
            a1 += f * Wout[HID + k];
        }
    }
#pragma unroll
    for (int off = 32; off > 0; off >>= 1) {
        a0 += __shfl_down(a0, off);
        a1 += __shfl_down(a1, off);
    }
    if (lane == 0) {
        outt[row * 2 + 0] = a0 + bout[0];
        outt[row * 2 + 1] = a1 + bout[1];
    }
}

// ------------------------------------------------------------- launch ----
extern "C" void kernel_launch(void* const* d_in, const int* in_sizes, int n_in,
                              void* d_out, int out_size, void* d_ws, size_t ws_size,
                              hipStream_t stream) {
    const float* obs  = (const float*)d_in[0];
    const float* h0   = (const float*)d_in[1];
    const float* Wih  = (const float*)d_in[2];
    const float* Whh  = (const float*)d_in[3];
    const float* bih  = (const float*)d_in[4];
    const float* bhh  = (const float*)d_in[5];
    const float* Wout = (const float*)d_in[6];
    const float* bout = (const float*)d_in[7];
    float* out = (float*)d_out;

    char* ws = (char*)d_ws;
    ushort* Wg = (ushort*)(ws);                 // 8 MB bf16 W_hh (permuted)
    ushort* hA = (ushort*)(ws + (8  << 20));    // 8 MB bf16 h ping
    ushort* hB = (ushort*)(ws + (16 << 20));    // 8 MB bf16 h pong
    float*  c  = (float* )(ws + (24 << 20));    // 16 MB fp32 c state (block-local layout)

    prep_kernel<<<4096, 256, 0, stream>>>((const float4*)Whh, (const float4*)h0,
                                          (ushort4*)Wg, (ushort4*)hA, (float4*)c,
                                          N_BATCH * HID / 4);

    ushort* hin = hA;
    ushort* hou = hB;
    for (int t = 0; t < OBSLEN; ++t) {
        const float* xt = obs + (size_t)(t == 0 ? 0 : (t - 1)) * N_BATCH * 2;
        // grid: 16 row-blocks x 16 col-blocks (256 output cols each = 4*HID total)
        lstm_step_kernel<<<dim3(N_BATCH / BM, (4 * HID) / 256), 512, 0, stream>>>(
            hin, Wg, xt, Wih, bih, bhh, c, hou);
        out_proj_kernel<<<N_BATCH / 4, 256, 0, stream>>>(
            hou, Wout, bout, out + (size_t)t * N_BATCH * 2);
        ushort* tmp = hin; hin = hou; hou = tmp;
    }
}